// Round 3
// baseline (266.519 us; speedup 1.0000x reference)
//
#include <hip/hip_runtime.h>
#include <stdint.h>
#include <math.h>

#define B_ 4
#define T_ 4096
#define C_ 1024
#define H_ 128

typedef __attribute__((ext_vector_type(8))) short s16x8;   // 8 bf16 (4 VGPRs)
typedef __attribute__((ext_vector_type(4))) float f32x4;   // MFMA accumulator

__device__ __forceinline__ unsigned short f2bf(float f) {
    union { float f; unsigned u; } v; v.f = f;
    unsigned r = v.u + 0x7fffu + ((v.u >> 16) & 1u);
    return (unsigned short)(r >> 16);
}

__device__ __forceinline__ s16x8 as_frag(uint4 u) {
    union { uint4 u; s16x8 s; } v; v.u = u; return v.s;
}

// DPP butterfly reduction across 16 contiguous lanes (a DPP "row").
// quad_perm xor1 = 0xB1, quad_perm xor2 = 0x4E, row_half_mirror = 0x141,
// row_mirror = 0x140. VALU-only: keeps the softmax chain off the LDS pipe.
#define DPP_STEP(x, ctrl, op)                                                  \
    x = op(x, __int_as_float(__builtin_amdgcn_update_dpp(                      \
               0, __float_as_int(x), ctrl, 0xF, 0xF, true)))

__device__ __forceinline__ float red16_max(float x) {
    DPP_STEP(x, 0xB1, fmaxf); DPP_STEP(x, 0x4E, fmaxf);
    DPP_STEP(x, 0x141, fmaxf); DPP_STEP(x, 0x140, fmaxf);
    return x;
}
__device__ __forceinline__ float addf(float a, float b) { return a + b; }
__device__ __forceinline__ float red16_sum(float x) {
    DPP_STEP(x, 0xB1, addf); DPP_STEP(x, 0x4E, addf);
    DPP_STEP(x, 0x141, addf); DPP_STEP(x, 0x140, addf);
    return x;
}

// softmax scale folded into Q at projection time: 1/sqrt(128) * log2(e)
#define QSC (0.0883883476f * 1.4426950408f)

// ---------------------------------------------------------------------------
// Kernel 1: W [1024][128] fp32 -> Wt [3*128][1024] bf16 (transposed, converted)
// ---------------------------------------------------------------------------
__global__ __launch_bounds__(256) void k_wt(const float* __restrict__ Wk,
                                            const float* __restrict__ Wq,
                                            const float* __restrict__ Wv,
                                            unsigned short* __restrict__ Wt) {
    __shared__ float tile[64][65];
    int w = blockIdx.z;  // 0=K, 1=Q, 2=V
    const float* W = (w == 0) ? Wk : (w == 1) ? Wq : Wv;
    int c0 = blockIdx.x * 64, h0 = blockIdx.y * 64;
    int tid = threadIdx.x;
#pragma unroll
    for (int k = 0; k < 16; k++) {
        int idx = tid + k * 256;
        int r = idx >> 6, c = idx & 63;
        tile[r][c] = W[(size_t)(c0 + r) * H_ + h0 + c];
    }
    __syncthreads();
#pragma unroll
    for (int k = 0; k < 16; k++) {
        int idx = tid + k * 256;
        int hh = idx >> 6, cc = idx & 63;
        Wt[(size_t)(w * H_ + h0 + hh) * C_ + c0 + cc] = f2bf(tile[cc][hh]);
    }
}

// ---------------------------------------------------------------------------
// Kernel 2: fused QKV GEMM, software-pipelined.
// 512 blocks: 256 row-tiles (64 rows) x 2 col-halves (192 cols).
// Ping-pong register double-buffer of x chunk AND Wt B-fragments: per-chunk
// serial cost is pack->LDS->MFMA; global latency overlaps previous chunk.
// ---------------------------------------------------------------------------
__global__ __launch_bounds__(256, 2) void k_qkv(const float* __restrict__ x,
                                                const unsigned short* __restrict__ Wt,
                                                unsigned short* __restrict__ Qb,
                                                unsigned short* __restrict__ Kb,
                                                unsigned short* __restrict__ Vt) {
    __shared__ unsigned short a_lds[64 * 72];  // 64 rows x 64 k, stride 72
    int tid = threadIdx.x;
    int wv = tid >> 6, lane = tid & 63, quad = lane >> 4, lo = lane & 15;
    int r0 = blockIdx.x * 64;
    int cb = blockIdx.y;
    int nt0 = wv * 3;

    f32x4 acc[3][4];
#pragma unroll
    for (int i = 0; i < 3; i++)
#pragma unroll
        for (int j = 0; j < 4; j++) acc[i][j] = (f32x4){0.f, 0.f, 0.f, 0.f};

    const int row_s = tid >> 2;
    const int seg_s = (tid & 3) * 16;
    size_t xbase = (size_t)(r0 + row_s) * C_ + seg_s;

    const unsigned short* wp[3];
#pragma unroll
    for (int nt = 0; nt < 3; nt++)
        wp[nt] = Wt + (size_t)(cb * 192 + (nt0 + nt) * 16 + lo) * C_ + quad * 8;

    auto pack_store = [&](const float4 (&f)[4]) {
        uint4 u0, u1;
        u0.x = (unsigned)f2bf(f[0].x) | ((unsigned)f2bf(f[0].y) << 16);
        u0.y = (unsigned)f2bf(f[0].z) | ((unsigned)f2bf(f[0].w) << 16);
        u0.z = (unsigned)f2bf(f[1].x) | ((unsigned)f2bf(f[1].y) << 16);
        u0.w = (unsigned)f2bf(f[1].z) | ((unsigned)f2bf(f[1].w) << 16);
        u1.x = (unsigned)f2bf(f[2].x) | ((unsigned)f2bf(f[2].y) << 16);
        u1.y = (unsigned)f2bf(f[2].z) | ((unsigned)f2bf(f[2].w) << 16);
        u1.z = (unsigned)f2bf(f[3].x) | ((unsigned)f2bf(f[3].y) << 16);
        u1.w = (unsigned)f2bf(f[3].z) | ((unsigned)f2bf(f[3].w) << 16);
        *(uint4*)&a_lds[row_s * 72 + seg_s] = u0;
        *(uint4*)&a_lds[row_s * 72 + seg_s + 8] = u1;
    };
    auto load_x = [&](float4 (&f)[4], int kc) {
        const float* xp = x + xbase + kc * 64;
#pragma unroll
        for (int j = 0; j < 4; j++) f[j] = *(const float4*)(xp + j * 4);
    };
    auto load_b = [&](s16x8 (&b)[3][2], int kc) {
#pragma unroll
        for (int nt = 0; nt < 3; nt++)
#pragma unroll
            for (int kh = 0; kh < 2; kh++)
                b[nt][kh] = *(const s16x8*)(wp[nt] + kc * 64 + kh * 32);
    };
    auto gemm = [&](const s16x8 (&b)[3][2]) {
        s16x8 af[4][2];
#pragma unroll
        for (int mt = 0; mt < 4; mt++)
#pragma unroll
            for (int kh = 0; kh < 2; kh++)
                af[mt][kh] = *(const s16x8*)&a_lds[(mt * 16 + lo) * 72 + kh * 32 + quad * 8];
#pragma unroll
        for (int nt = 0; nt < 3; nt++)
#pragma unroll
            for (int kh = 0; kh < 2; kh++)
#pragma unroll
                for (int mt = 0; mt < 4; mt++)
                    acc[nt][mt] = __builtin_amdgcn_mfma_f32_16x16x32_bf16(
                        af[mt][kh], b[nt][kh], acc[nt][mt], 0, 0, 0);
    };

    float4 xa[4], xb[4];
    s16x8 ba[3][2], bb[3][2];
    load_x(xa, 0);
    load_b(ba, 0);

    for (int kc2 = 0; kc2 < 8; kc2++) {
        int e = kc2 * 2;
        // even chunk e: consume xa/ba; prefetch xb/bb for e+1
        pack_store(xa);
        load_x(xb, e + 1);
        __syncthreads();
        load_b(bb, e + 1);
        gemm(ba);
        __syncthreads();
        // odd chunk e+1: consume xb/bb; prefetch xa/ba for e+2
        pack_store(xb);
        if (kc2 < 7) load_x(xa, e + 2);
        __syncthreads();
        if (kc2 < 7) load_b(ba, e + 2);
        gemm(bb);
        __syncthreads();
    }

    // Epilogue. C-layout: row = mt*16 + quad*4 + r, col = cb*192 + (nt0+nt)*16 + lo
#pragma unroll
    for (int nt = 0; nt < 3; nt++) {
        int col = cb * 192 + (nt0 + nt) * 16 + lo;
        int w = col >> 7, h = col & 127;
#pragma unroll
        for (int mt = 0; mt < 4; mt++) {
            int mrow = r0 + mt * 16 + quad * 4;
            if (w == 2) {
                int b = mrow >> 12, t = mrow & 4095;
                uint2 pk;
                pk.x = (unsigned)f2bf(acc[nt][mt][0]) | ((unsigned)f2bf(acc[nt][mt][1]) << 16);
                pk.y = (unsigned)f2bf(acc[nt][mt][2]) | ((unsigned)f2bf(acc[nt][mt][3]) << 16);
                *(uint2*)(Vt + (size_t)(b * H_ + h) * T_ + t) = pk;
            } else if (w == 1) {
                unsigned short* dst = Qb + (size_t)mrow * H_ + h;
#pragma unroll
                for (int r = 0; r < 4; r++)
                    dst[(size_t)r * H_] = f2bf(acc[nt][mt][r] * QSC);
            } else {
                unsigned short* dst = Kb + (size_t)mrow * H_ + h;
#pragma unroll
                for (int r = 0; r < 4; r++)
                    dst[(size_t)r * H_] = f2bf(acc[nt][mt][r]);
            }
        }
    }
}

// ---------------------------------------------------------------------------
// Kernel 3: causal flash attention, split-KV, software-pipelined.
// Next K/V tile prefetched into registers while current tile computes;
// DPP (VALU-only) softmax reductions.
// ---------------------------------------------------------------------------
template <int NSPLIT>
__global__ __launch_bounds__(256, 4) void k_attn(const unsigned short* __restrict__ Qb,
                                                 const unsigned short* __restrict__ Kb,
                                                 const unsigned short* __restrict__ Vt,
                                                 float* __restrict__ Opart,
                                                 float* __restrict__ Mpart,
                                                 float* __restrict__ Lpart,
                                                 float* __restrict__ out) {
    __shared__ uint4 kbuf[64 * 16];
    __shared__ uint4 vbuf[128 * 8];
    __shared__ unsigned short pbuf[4][16 * 64];

    int tid = threadIdx.x;
    int wv = tid >> 6, lane = tid & 63, quad = lane >> 4, lo = lane & 15;

    int id = blockIdx.x;
    int qt = 63 - id / (4 * NSPLIT);   // largest-first
    int rem = id % (4 * NSPLIT);
    int batch = rem / NSPLIT;
    int split = rem % NSPLIT;
    int m0 = qt * 64 + wv * 16;

    s16x8 qf[4];
    size_t qrow = (size_t)(batch * T_ + m0 + lo) * H_;
#pragma unroll
    for (int ks = 0; ks < 4; ks++)
        qf[ks] = *(const s16x8*)(Qb + qrow + ks * 32 + quad * 8);

    f32x4 acc_o[8];
#pragma unroll
    for (int o = 0; o < 8; o++) acc_o[o] = (f32x4){0.f, 0.f, 0.f, 0.f};
    float m_i[4], l_i[4];
#pragma unroll
    for (int r = 0; r < 4; r++) { m_i[r] = -INFINITY; l_i[r] = 0.f; }

    const int srow_k = tid >> 2, sseg_k = (tid & 3) * 4;
    const int srow_v = tid >> 1, sseg_v = (tid & 1) * 4;

    uint4 kr[4], vr[4];
    auto load_tiles = [&](int kv0) {
        const uint4* kg = (const uint4*)(Kb + (size_t)(batch * T_ + kv0 + srow_k) * H_);
#pragma unroll
        for (int i = 0; i < 4; i++) kr[i] = kg[sseg_k + i];
        const uint4* vg = (const uint4*)(Vt + (size_t)(batch * H_ + srow_v) * T_ + kv0);
#pragma unroll
        for (int i = 0; i < 4; i++) vr[i] = vg[sseg_v + i];
    };

    load_tiles(split * 64);

    for (int t = split; t <= qt; t += NSPLIT) {
        int kv0 = t * 64;
        // stage prefetched registers -> LDS (swizzled)
#pragma unroll
        for (int i = 0; i < 4; i++)
            kbuf[srow_k * 16 + ((sseg_k + i) ^ (srow_k & 15))] = kr[i];
#pragma unroll
        for (int i = 0; i < 4; i++)
            vbuf[srow_v * 8 + ((sseg_v + i) ^ (srow_v & 7))] = vr[i];
        __syncthreads();
        // prefetch next tile; latency overlaps this iteration's compute
        if (t + NSPLIT <= qt) load_tiles((t + NSPLIT) * 64);

        // S = Q K^T (logits already in log2 domain; Q pre-scaled)
        f32x4 s_acc[4];
#pragma unroll
        for (int nt = 0; nt < 4; nt++) s_acc[nt] = (f32x4){0.f, 0.f, 0.f, 0.f};
#pragma unroll
        for (int ks = 0; ks < 4; ks++) {
#pragma unroll
            for (int nt = 0; nt < 4; nt++) {
                s16x8 kf = as_frag(kbuf[(nt * 16 + lo) * 16 + ((ks * 4 + quad) ^ lo)]);
                s_acc[nt] = __builtin_amdgcn_mfma_f32_16x16x32_bf16(qf[ks], kf, s_acc[nt], 0, 0, 0);
            }
        }

        float p[4][4];
        bool diag = (t == qt);
#pragma unroll
        for (int nt = 0; nt < 4; nt++)
#pragma unroll
            for (int r = 0; r < 4; r++) {
                float sv = s_acc[nt][r];
                if (diag) {
                    int colg = kv0 + nt * 16 + lo;
                    int rowg = m0 + quad * 4 + r;
                    if (colg > rowg) sv = -INFINITY;
                }
                p[nt][r] = sv;
            }
        float mnew[4], alpha[4];
#pragma unroll
        for (int r = 0; r < 4; r++) {
            float mx = fmaxf(fmaxf(p[0][r], p[1][r]), fmaxf(p[2][r], p[3][r]));
            mx = red16_max(mx);
            mnew[r] = fmaxf(m_i[r], mx);
            alpha[r] = exp2f(m_i[r] - mnew[r]);
            m_i[r] = mnew[r];
        }
        float rs[4] = {0.f, 0.f, 0.f, 0.f};
#pragma unroll
        for (int nt = 0; nt < 4; nt++)
#pragma unroll
            for (int r = 0; r < 4; r++) {
                float pv = exp2f(p[nt][r] - mnew[r]);
                p[nt][r] = pv;
                rs[r] += pv;
            }
#pragma unroll
        for (int r = 0; r < 4; r++) {
            l_i[r] = l_i[r] * alpha[r] + red16_sum(rs[r]);
        }
#pragma unroll
        for (int o = 0; o < 8; o++)
#pragma unroll
            for (int r = 0; r < 4; r++) acc_o[o][r] *= alpha[r];

        // P: C-layout -> A-layout via per-wave LDS
        unsigned short* pb = pbuf[wv];
#pragma unroll
        for (int nt = 0; nt < 4; nt++)
#pragma unroll
            for (int r = 0; r < 4; r++) {
                int prow = quad * 4 + r;
                int col = nt * 16 + lo;
                int seg = col >> 3, off = col & 7;
                pb[prow * 64 + ((seg ^ (prow & 7)) << 3) + off] = f2bf(p[nt][r]);
            }
        s16x8 pf[2];
#pragma unroll
        for (int kss = 0; kss < 2; kss++) {
            int seg = kss * 4 + quad;
            pf[kss] = *(const s16x8*)&pb[lo * 64 + ((seg ^ (lo & 7)) << 3)];
        }

#pragma unroll
        for (int kss = 0; kss < 2; kss++)
#pragma unroll
            for (int o = 0; o < 8; o++) {
                int vrow = o * 16 + lo;
                s16x8 vf = as_frag(vbuf[vrow * 8 + ((kss * 4 + quad) ^ (vrow & 7))]);
                acc_o[o] = __builtin_amdgcn_mfma_f32_16x16x32_bf16(pf[kss], vf, acc_o[o], 0, 0, 0);
            }
        __syncthreads();
    }

    if (NSPLIT == 1) {
        float inv[4];
#pragma unroll
        for (int r = 0; r < 4; r++) inv[r] = 1.0f / l_i[r];
#pragma unroll
        for (int o = 0; o < 8; o++)
#pragma unroll
            for (int r = 0; r < 4; r++) {
                int rowg = batch * T_ + m0 + quad * 4 + r;
                out[(size_t)rowg * H_ + o * 16 + lo] = acc_o[o][r] * inv[r];
            }
    } else {
        float* Op = Opart + (size_t)split * (16384 * 128);
#pragma unroll
        for (int o = 0; o < 8; o++)
#pragma unroll
            for (int r = 0; r < 4; r++) {
                int rowg = batch * T_ + m0 + quad * 4 + r;
                Op[(size_t)rowg * H_ + o * 16 + lo] = acc_o[o][r];
            }
        if (lo == 0) {
#pragma unroll
            for (int r = 0; r < 4; r++) {
                int rowg = batch * T_ + m0 + quad * 4 + r;
                Mpart[split * 16384 + rowg] = m_i[r];
                Lpart[split * 16384 + rowg] = l_i[r];
            }
        }
    }
}

// ---------------------------------------------------------------------------
// Kernel 4: combine split-KV partials. 8 rows/block, float4 per thread.
// ---------------------------------------------------------------------------
template <int NSPLIT>
__global__ __launch_bounds__(256) void k_comb(const float* __restrict__ Opart,
                                              const float* __restrict__ Mpart,
                                              const float* __restrict__ Lpart,
                                              float* __restrict__ out) {
    int tid = threadIdx.x;
    int row = blockIdx.x * 8 + (tid >> 5);
    int h4 = (tid & 31) * 4;
    float m[NSPLIT], l[NSPLIT];
    float M = -INFINITY;
#pragma unroll
    for (int s = 0; s < NSPLIT; s++) {
        m[s] = Mpart[s * 16384 + row];
        l[s] = Lpart[s * 16384 + row];
        M = fmaxf(M, m[s]);
    }
    float4 o = {0.f, 0.f, 0.f, 0.f};
    float den = 0.f;
#pragma unroll
    for (int s = 0; s < NSPLIT; s++) {
        float w = exp2f(m[s] - M);
        den += w * l[s];
        float4 v = *(const float4*)(Opart + ((size_t)s * 16384 + row) * H_ + h4);
        o.x += w * v.x; o.y += w * v.y; o.z += w * v.z; o.w += w * v.w;
    }
    float inv = 1.0f / den;
    float4 r = {o.x * inv, o.y * inv, o.z * inv, o.w * inv};
    *(float4*)(out + (size_t)row * H_ + h4) = r;
}

// ---------------------------------------------------------------------------
extern "C" void kernel_launch(void* const* d_in, const int* in_sizes, int n_in,
                              void* d_out, int out_size, void* d_ws, size_t ws_size,
                              hipStream_t stream) {
    const float* x  = (const float*)d_in[0];
    const float* Wk = (const float*)d_in[1];
    const float* Wq = (const float*)d_in[2];
    const float* Wv = (const float*)d_in[3];
    char* ws = (char*)d_ws;
    unsigned short* Wt = (unsigned short*)ws;                 // 768 KB
    unsigned short* Qb = (unsigned short*)(ws + (1u << 20));  // 4 MB
    unsigned short* Kb = (unsigned short*)(ws + (5u << 20));  // 4 MB
    unsigned short* Vt = (unsigned short*)(ws + (9u << 20));  // 4 MB -> end 13 MB
    float* out = (float*)d_out;

    const size_t SPLIT_O = (size_t)16384 * 128 * 4;  // 8 MB per split
    const size_t base = (size_t)13 << 20;
    const size_t need4 = base + 4 * SPLIT_O + 8 * 65536;
    const size_t need2 = base + 2 * SPLIT_O + 4 * 65536;

    k_wt  <<<dim3(16, 2, 3), 256, 0, stream>>>(Wk, Wq, Wv, Wt);
    k_qkv <<<dim3(256, 2), 256, 0, stream>>>(x, Wt, Qb, Kb, Vt);

    if (ws_size >= need4) {
        float* Op = (float*)(ws + base);
        float* Mp = (float*)(ws + base + 4 * SPLIT_O);
        float* Lp = (float*)(ws + base + 4 * SPLIT_O + 4 * 65536);
        k_attn<4><<<1024, 256, 0, stream>>>(Qb, Kb, Vt, Op, Mp, Lp, out);
        k_comb<4><<<2048, 256, 0, stream>>>(Op, Mp, Lp, out);
    } else if (ws_size >= need2) {
        float* Op = (float*)(ws + base);
        float* Mp = (float*)(ws + base + 2 * SPLIT_O);
        float* Lp = (float*)(ws + base + 2 * SPLIT_O + 2 * 65536);
        k_attn<2><<<512, 256, 0, stream>>>(Qb, Kb, Vt, Op, Mp, Lp, out);
        k_comb<2><<<2048, 256, 0, stream>>>(Op, Mp, Lp, out);
    } else {
        k_attn<1><<<256, 256, 0, stream>>>(Qb, Kb, Vt, nullptr, nullptr, nullptr, out);
    }
}

// Round 4
// 180.103 us; speedup vs baseline: 1.4798x; 1.4798x over previous
//
#include <hip/hip_runtime.h>
#include <stdint.h>
#include <math.h>

#define B_ 4
#define T_ 4096
#define C_ 1024
#define H_ 128

typedef __attribute__((ext_vector_type(8))) short s16x8;   // 8 bf16 (4 VGPRs)
typedef __attribute__((ext_vector_type(4))) float f32x4;   // MFMA accumulator

__device__ __forceinline__ unsigned short f2bf(float f) {
    union { float f; unsigned u; } v; v.f = f;
    unsigned r = v.u + 0x7fffu + ((v.u >> 16) & 1u);
    return (unsigned short)(r >> 16);
}

__device__ __forceinline__ s16x8 as_frag(uint4 u) {
    union { uint4 u; s16x8 s; } v; v.u = u; return v.s;
}

// DPP butterfly reduction across 16 contiguous lanes (VALU-only, off LDS pipe).
#define DPP_STEP(x, ctrl, op)                                                  \
    x = op(x, __int_as_float(__builtin_amdgcn_update_dpp(                      \
               0, __float_as_int(x), ctrl, 0xF, 0xF, true)))

__device__ __forceinline__ float red16_max(float x) {
    DPP_STEP(x, 0xB1, fmaxf); DPP_STEP(x, 0x4E, fmaxf);
    DPP_STEP(x, 0x141, fmaxf); DPP_STEP(x, 0x140, fmaxf);
    return x;
}
__device__ __forceinline__ float addf(float a, float b) { return a + b; }
__device__ __forceinline__ float red16_sum(float x) {
    DPP_STEP(x, 0xB1, addf); DPP_STEP(x, 0x4E, addf);
    DPP_STEP(x, 0x141, addf); DPP_STEP(x, 0x140, addf);
    return x;
}

// softmax scale folded into Q at projection time: 1/sqrt(128) * log2(e)
#define QSC (0.0883883476f * 1.4426950408f)

// ---------------------------------------------------------------------------
// Kernel 1: W [1024][128] fp32 -> Wt [3*128][1024] bf16 (transposed, converted)
// ---------------------------------------------------------------------------
__global__ __launch_bounds__(256) void k_wt(const float* __restrict__ Wk,
                                            const float* __restrict__ Wq,
                                            const float* __restrict__ Wv,
                                            unsigned short* __restrict__ Wt) {
    __shared__ float tile[64][65];
    int w = blockIdx.z;  // 0=K, 1=Q, 2=V
    const float* W = (w == 0) ? Wk : (w == 1) ? Wq : Wv;
    int c0 = blockIdx.x * 64, h0 = blockIdx.y * 64;
    int tid = threadIdx.x;
#pragma unroll
    for (int k = 0; k < 16; k++) {
        int idx = tid + k * 256;
        int r = idx >> 6, c = idx & 63;
        tile[r][c] = W[(size_t)(c0 + r) * H_ + h0 + c];
    }
    __syncthreads();
#pragma unroll
    for (int k = 0; k < 16; k++) {
        int idx = tid + k * 256;
        int hh = idx >> 6, cc = idx & 63;
        Wt[(size_t)(w * H_ + h0 + hh) * C_ + c0 + cc] = f2bf(tile[cc][hh]);
    }
}

// ---------------------------------------------------------------------------
// Kernel 2: fused QKV GEMM, software-pipelined (register ping-pong).
// 512 blocks: 256 row-tiles (64 rows) x 2 col-halves (192 cols).
// launch_bounds(256,2): VGPR cap 256 -> no spill hazard from the double buffers.
// ---------------------------------------------------------------------------
__global__ __launch_bounds__(256, 2) void k_qkv(const float* __restrict__ x,
                                                const unsigned short* __restrict__ Wt,
                                                unsigned short* __restrict__ Qb,
                                                unsigned short* __restrict__ Kb,
                                                unsigned short* __restrict__ Vt) {
    __shared__ unsigned short a_lds[64 * 72];  // 64 rows x 64 k, stride 72
    int tid = threadIdx.x;
    int wv = tid >> 6, lane = tid & 63, quad = lane >> 4, lo = lane & 15;
    int r0 = blockIdx.x * 64;
    int cb = blockIdx.y;
    int nt0 = wv * 3;

    f32x4 acc[3][4];
#pragma unroll
    for (int i = 0; i < 3; i++)
#pragma unroll
        for (int j = 0; j < 4; j++) acc[i][j] = (f32x4){0.f, 0.f, 0.f, 0.f};

    const int row_s = tid >> 2;
    const int seg_s = (tid & 3) * 16;
    size_t xbase = (size_t)(r0 + row_s) * C_ + seg_s;

    const unsigned short* wp[3];
#pragma unroll
    for (int nt = 0; nt < 3; nt++)
        wp[nt] = Wt + (size_t)(cb * 192 + (nt0 + nt) * 16 + lo) * C_ + quad * 8;

    auto pack_store = [&](const float4 (&f)[4]) {
        uint4 u0, u1;
        u0.x = (unsigned)f2bf(f[0].x) | ((unsigned)f2bf(f[0].y) << 16);
        u0.y = (unsigned)f2bf(f[0].z) | ((unsigned)f2bf(f[0].w) << 16);
        u0.z = (unsigned)f2bf(f[1].x) | ((unsigned)f2bf(f[1].y) << 16);
        u0.w = (unsigned)f2bf(f[1].z) | ((unsigned)f2bf(f[1].w) << 16);
        u1.x = (unsigned)f2bf(f[2].x) | ((unsigned)f2bf(f[2].y) << 16);
        u1.y = (unsigned)f2bf(f[2].z) | ((unsigned)f2bf(f[2].w) << 16);
        u1.z = (unsigned)f2bf(f[3].x) | ((unsigned)f2bf(f[3].y) << 16);
        u1.w = (unsigned)f2bf(f[3].z) | ((unsigned)f2bf(f[3].w) << 16);
        *(uint4*)&a_lds[row_s * 72 + seg_s] = u0;
        *(uint4*)&a_lds[row_s * 72 + seg_s + 8] = u1;
    };
    auto load_x = [&](float4 (&f)[4], int kc) {
        const float* xp = x + xbase + kc * 64;
#pragma unroll
        for (int j = 0; j < 4; j++) f[j] = *(const float4*)(xp + j * 4);
    };
    auto load_b = [&](s16x8 (&b)[3][2], int kc) {
#pragma unroll
        for (int nt = 0; nt < 3; nt++)
#pragma unroll
            for (int kh = 0; kh < 2; kh++)
                b[nt][kh] = *(const s16x8*)(wp[nt] + kc * 64 + kh * 32);
    };
    auto gemm = [&](const s16x8 (&b)[3][2]) {
        s16x8 af[4][2];
#pragma unroll
        for (int mt = 0; mt < 4; mt++)
#pragma unroll
            for (int kh = 0; kh < 2; kh++)
                af[mt][kh] = *(const s16x8*)&a_lds[(mt * 16 + lo) * 72 + kh * 32 + quad * 8];
#pragma unroll
        for (int nt = 0; nt < 3; nt++)
#pragma unroll
            for (int kh = 0; kh < 2; kh++)
#pragma unroll
                for (int mt = 0; mt < 4; mt++)
                    acc[nt][mt] = __builtin_amdgcn_mfma_f32_16x16x32_bf16(
                        af[mt][kh], b[nt][kh], acc[nt][mt], 0, 0, 0);
    };

    float4 xa[4], xb[4];
    s16x8 ba[3][2], bb[3][2];
    load_x(xa, 0);
    load_b(ba, 0);

    for (int kc2 = 0; kc2 < 8; kc2++) {
        int e = kc2 * 2;
        pack_store(xa);
        load_x(xb, e + 1);
        __syncthreads();
        load_b(bb, e + 1);
        gemm(ba);
        __syncthreads();
        pack_store(xb);
        if (kc2 < 7) load_x(xa, e + 2);
        __syncthreads();
        if (kc2 < 7) load_b(ba, e + 2);
        gemm(bb);
        __syncthreads();
    }

    // Epilogue. C-layout: row = mt*16 + quad*4 + r, col = cb*192 + (nt0+nt)*16 + lo
#pragma unroll
    for (int nt = 0; nt < 3; nt++) {
        int col = cb * 192 + (nt0 + nt) * 16 + lo;
        int w = col >> 7, h = col & 127;
#pragma unroll
        for (int mt = 0; mt < 4; mt++) {
            int mrow = r0 + mt * 16 + quad * 4;
            if (w == 2) {
                int b = mrow >> 12, t = mrow & 4095;
                uint2 pk;
                pk.x = (unsigned)f2bf(acc[nt][mt][0]) | ((unsigned)f2bf(acc[nt][mt][1]) << 16);
                pk.y = (unsigned)f2bf(acc[nt][mt][2]) | ((unsigned)f2bf(acc[nt][mt][3]) << 16);
                *(uint2*)(Vt + (size_t)(b * H_ + h) * T_ + t) = pk;
            } else if (w == 1) {
                unsigned short* dst = Qb + (size_t)mrow * H_ + h;
#pragma unroll
                for (int r = 0; r < 4; r++)
                    dst[(size_t)r * H_] = f2bf(acc[nt][mt][r] * QSC);
            } else {
                unsigned short* dst = Kb + (size_t)mrow * H_ + h;
#pragma unroll
                for (int r = 0; r < 4; r++)
                    dst[(size_t)r * H_] = f2bf(acc[nt][mt][r]);
            }
        }
    }
}

// ---------------------------------------------------------------------------
// Kernel 3: causal flash attention, split-KV.
// Register prefetch of next K/V tile in EXPLICIT SCALARS (no arrays -> no
// scratch alloca). launch_bounds(256,3): VGPR cap ~170 covers ~150 live regs
// (acc_o 32 + qf 16 + s_acc/p 32 + prefetch 32 + softmax/temps) -> no spill.
// ---------------------------------------------------------------------------
#define LOAD_KV(kv0)                                                            \
    do {                                                                        \
        const uint4* kg = (const uint4*)(Kb + (size_t)(batch * T_ + (kv0) + srow_k) * H_); \
        pk0 = kg[sseg_k + 0]; pk1 = kg[sseg_k + 1];                             \
        pk2 = kg[sseg_k + 2]; pk3 = kg[sseg_k + 3];                             \
        const uint4* vg = (const uint4*)(Vt + (size_t)(batch * H_ + srow_v) * T_ + (kv0)); \
        pv0 = vg[sseg_v + 0]; pv1 = vg[sseg_v + 1];                             \
        pv2 = vg[sseg_v + 2]; pv3 = vg[sseg_v + 3];                             \
    } while (0)

template <int NSPLIT>
__global__ __launch_bounds__(256, 3) void k_attn(const unsigned short* __restrict__ Qb,
                                                 const unsigned short* __restrict__ Kb,
                                                 const unsigned short* __restrict__ Vt,
                                                 float* __restrict__ Opart,
                                                 float* __restrict__ Mpart,
                                                 float* __restrict__ Lpart,
                                                 float* __restrict__ out) {
    __shared__ uint4 kbuf[64 * 16];
    __shared__ uint4 vbuf[128 * 8];
    __shared__ unsigned short pbuf[4][16 * 64];

    int tid = threadIdx.x;
    int wv = tid >> 6, lane = tid & 63, quad = lane >> 4, lo = lane & 15;

    int id = blockIdx.x;
    int qt = 63 - id / (4 * NSPLIT);   // largest-first
    int rem = id % (4 * NSPLIT);
    int batch = rem / NSPLIT;
    int split = rem % NSPLIT;
    int m0 = qt * 64 + wv * 16;

    s16x8 qf[4];
    size_t qrow = (size_t)(batch * T_ + m0 + lo) * H_;
#pragma unroll
    for (int ks = 0; ks < 4; ks++)
        qf[ks] = *(const s16x8*)(Qb + qrow + ks * 32 + quad * 8);

    f32x4 acc_o[8];
#pragma unroll
    for (int o = 0; o < 8; o++) acc_o[o] = (f32x4){0.f, 0.f, 0.f, 0.f};
    float m_i[4], l_i[4];
#pragma unroll
    for (int r = 0; r < 4; r++) { m_i[r] = -INFINITY; l_i[r] = 0.f; }

    const int srow_k = tid >> 2, sseg_k = (tid & 3) * 4;
    const int srow_v = tid >> 1, sseg_v = (tid & 1) * 4;

    uint4 pk0, pk1, pk2, pk3, pv0, pv1, pv2, pv3;
    LOAD_KV(split * 64);

    for (int t = split; t <= qt; t += NSPLIT) {
        int kv0 = t * 64;
        // stage prefetched registers -> LDS (swizzled)
        kbuf[srow_k * 16 + ((sseg_k + 0) ^ (srow_k & 15))] = pk0;
        kbuf[srow_k * 16 + ((sseg_k + 1) ^ (srow_k & 15))] = pk1;
        kbuf[srow_k * 16 + ((sseg_k + 2) ^ (srow_k & 15))] = pk2;
        kbuf[srow_k * 16 + ((sseg_k + 3) ^ (srow_k & 15))] = pk3;
        vbuf[srow_v * 8 + ((sseg_v + 0) ^ (srow_v & 7))] = pv0;
        vbuf[srow_v * 8 + ((sseg_v + 1) ^ (srow_v & 7))] = pv1;
        vbuf[srow_v * 8 + ((sseg_v + 2) ^ (srow_v & 7))] = pv2;
        vbuf[srow_v * 8 + ((sseg_v + 3) ^ (srow_v & 7))] = pv3;
        __syncthreads();
        // prefetch next tile; global latency overlaps this iteration's compute
        if (t + NSPLIT <= qt) LOAD_KV((t + NSPLIT) * 64);

        // S = Q K^T (logits already in log2 domain; Q pre-scaled)
        f32x4 s_acc[4];
#pragma unroll
        for (int nt = 0; nt < 4; nt++) s_acc[nt] = (f32x4){0.f, 0.f, 0.f, 0.f};
#pragma unroll
        for (int ks = 0; ks < 4; ks++) {
#pragma unroll
            for (int nt = 0; nt < 4; nt++) {
                s16x8 kf = as_frag(kbuf[(nt * 16 + lo) * 16 + ((ks * 4 + quad) ^ lo)]);
                s_acc[nt] = __builtin_amdgcn_mfma_f32_16x16x32_bf16(qf[ks], kf, s_acc[nt], 0, 0, 0);
            }
        }

        float p[4][4];
        bool diag = (t == qt);
#pragma unroll
        for (int nt = 0; nt < 4; nt++)
#pragma unroll
            for (int r = 0; r < 4; r++) {
                float sv = s_acc[nt][r];
                if (diag) {
                    int colg = kv0 + nt * 16 + lo;
                    int rowg = m0 + quad * 4 + r;
                    if (colg > rowg) sv = -INFINITY;
                }
                p[nt][r] = sv;
            }
        float mnew[4], alpha[4];
#pragma unroll
        for (int r = 0; r < 4; r++) {
            float mx = fmaxf(fmaxf(p[0][r], p[1][r]), fmaxf(p[2][r], p[3][r]));
            mx = red16_max(mx);
            mnew[r] = fmaxf(m_i[r], mx);
            alpha[r] = exp2f(m_i[r] - mnew[r]);
            m_i[r] = mnew[r];
        }
        float rs[4] = {0.f, 0.f, 0.f, 0.f};
#pragma unroll
        for (int nt = 0; nt < 4; nt++)
#pragma unroll
            for (int r = 0; r < 4; r++) {
                float pv = exp2f(p[nt][r] - mnew[r]);
                p[nt][r] = pv;
                rs[r] += pv;
            }
#pragma unroll
        for (int r = 0; r < 4; r++) {
            l_i[r] = l_i[r] * alpha[r] + red16_sum(rs[r]);
        }
#pragma unroll
        for (int o = 0; o < 8; o++)
#pragma unroll
            for (int r = 0; r < 4; r++) acc_o[o][r] *= alpha[r];

        // P: C-layout -> A-layout via per-wave LDS
        unsigned short* pb = pbuf[wv];
#pragma unroll
        for (int nt = 0; nt < 4; nt++)
#pragma unroll
            for (int r = 0; r < 4; r++) {
                int prow = quad * 4 + r;
                int col = nt * 16 + lo;
                int seg = col >> 3, off = col & 7;
                pb[prow * 64 + ((seg ^ (prow & 7)) << 3) + off] = f2bf(p[nt][r]);
            }
        s16x8 pf[2];
#pragma unroll
        for (int kss = 0; kss < 2; kss++) {
            int seg = kss * 4 + quad;
            pf[kss] = *(const s16x8*)&pb[lo * 64 + ((seg ^ (lo & 7)) << 3)];
        }

#pragma unroll
        for (int kss = 0; kss < 2; kss++)
#pragma unroll
            for (int o = 0; o < 8; o++) {
                int vrow = o * 16 + lo;
                s16x8 vf = as_frag(vbuf[vrow * 8 + ((kss * 4 + quad) ^ (vrow & 7))]);
                acc_o[o] = __builtin_amdgcn_mfma_f32_16x16x32_bf16(pf[kss], vf, acc_o[o], 0, 0, 0);
            }
        __syncthreads();
    }

    if (NSPLIT == 1) {
        float inv[4];
#pragma unroll
        for (int r = 0; r < 4; r++) inv[r] = 1.0f / l_i[r];
#pragma unroll
        for (int o = 0; o < 8; o++)
#pragma unroll
            for (int r = 0; r < 4; r++) {
                int rowg = batch * T_ + m0 + quad * 4 + r;
                out[(size_t)rowg * H_ + o * 16 + lo] = acc_o[o][r] * inv[r];
            }
    } else {
        float* Op = Opart + (size_t)split * (16384 * 128);
#pragma unroll
        for (int o = 0; o < 8; o++)
#pragma unroll
            for (int r = 0; r < 4; r++) {
                int rowg = batch * T_ + m0 + quad * 4 + r;
                Op[(size_t)rowg * H_ + o * 16 + lo] = acc_o[o][r];
            }
        if (lo == 0) {
#pragma unroll
            for (int r = 0; r < 4; r++) {
                int rowg = batch * T_ + m0 + quad * 4 + r;
                Mpart[split * 16384 + rowg] = m_i[r];
                Lpart[split * 16384 + rowg] = l_i[r];
            }
        }
    }
}

// ---------------------------------------------------------------------------
// Kernel 4: combine split-KV partials. 8 rows/block, float4 per thread.
// ---------------------------------------------------------------------------
template <int NSPLIT>
__global__ __launch_bounds__(256) void k_comb(const float* __restrict__ Opart,
                                              const float* __restrict__ Mpart,
                                              const float* __restrict__ Lpart,
                                              float* __restrict__ out) {
    int tid = threadIdx.x;
    int row = blockIdx.x * 8 + (tid >> 5);
    int h4 = (tid & 31) * 4;
    float m[NSPLIT], l[NSPLIT];
    float M = -INFINITY;
#pragma unroll
    for (int s = 0; s < NSPLIT; s++) {
        m[s] = Mpart[s * 16384 + row];
        l[s] = Lpart[s * 16384 + row];
        M = fmaxf(M, m[s]);
    }
    float4 o = {0.f, 0.f, 0.f, 0.f};
    float den = 0.f;
#pragma unroll
    for (int s = 0; s < NSPLIT; s++) {
        float w = exp2f(m[s] - M);
        den += w * l[s];
        float4 v = *(const float4*)(Opart + ((size_t)s * 16384 + row) * H_ + h4);
        o.x += w * v.x; o.y += w * v.y; o.z += w * v.z; o.w += w * v.w;
    }
    float inv = 1.0f / den;
    float4 r = {o.x * inv, o.y * inv, o.z * inv, o.w * inv};
    *(float4*)(out + (size_t)row * H_ + h4) = r;
}

// ---------------------------------------------------------------------------
extern "C" void kernel_launch(void* const* d_in, const int* in_sizes, int n_in,
                              void* d_out, int out_size, void* d_ws, size_t ws_size,
                              hipStream_t stream) {
    const float* x  = (const float*)d_in[0];
    const float* Wk = (const float*)d_in[1];
    const float* Wq = (const float*)d_in[2];
    const float* Wv = (const float*)d_in[3];
    char* ws = (char*)d_ws;
    unsigned short* Wt = (unsigned short*)ws;                 // 768 KB
    unsigned short* Qb = (unsigned short*)(ws + (1u << 20));  // 4 MB
    unsigned short* Kb = (unsigned short*)(ws + (5u << 20));  // 4 MB
    unsigned short* Vt = (unsigned short*)(ws + (9u << 20));  // 4 MB -> end 13 MB
    float* out = (float*)d_out;

    const size_t SPLIT_O = (size_t)16384 * 128 * 4;  // 8 MB per split
    const size_t base = (size_t)13 << 20;
    const size_t need4 = base + 4 * SPLIT_O + 8 * 65536;
    const size_t need2 = base + 2 * SPLIT_O + 4 * 65536;

    k_wt  <<<dim3(16, 2, 3), 256, 0, stream>>>(Wk, Wq, Wv, Wt);
    k_qkv <<<dim3(256, 2), 256, 0, stream>>>(x, Wt, Qb, Kb, Vt);

    if (ws_size >= need4) {
        float* Op = (float*)(ws + base);
        float* Mp = (float*)(ws + base + 4 * SPLIT_O);
        float* Lp = (float*)(ws + base + 4 * SPLIT_O + 4 * 65536);
        k_attn<4><<<1024, 256, 0, stream>>>(Qb, Kb, Vt, Op, Mp, Lp, out);
        k_comb<4><<<2048, 256, 0, stream>>>(Op, Mp, Lp, out);
    } else if (ws_size >= need2) {
        float* Op = (float*)(ws + base);
        float* Mp = (float*)(ws + base + 2 * SPLIT_O);
        float* Lp = (float*)(ws + base + 2 * SPLIT_O + 2 * 65536);
        k_attn<2><<<512, 256, 0, stream>>>(Qb, Kb, Vt, Op, Mp, Lp, out);
        k_comb<2><<<2048, 256, 0, stream>>>(Op, Mp, Lp, out);
    } else {
        k_attn<1><<<256, 256, 0, stream>>>(Qb, Kb, Vt, nullptr, nullptr, nullptr, out);
    }
}